// Round 5
// baseline (261.518 us; speedup 1.0000x reference)
//
#include <hip/hip_runtime.h>

// YOLO loss reduction: B=512, 3136 cells/sample, 15 slots/cell, fp32, sum.
//
// History: R5 slot-stream 76us. R6 batch-8 reg pipeline 72us (collapsed,
// VGPR=60). R7 depth-2 reg + residency 71us (collapsed, VGPR=20; occupancy
// 32->53% with ZERO dur change). R9 LDS pipeline 86us (barrier convoy,
// VALUBusy 14%). R10 asm depth-4 ring 86us (VGPR=28: ring bounced through
// accvgpr/scratch, never 16-deep).
// Synthesis: no pipe saturated (VALU 24%, HBM 17%, LDS 0), occupancy-
// insensitive, pipelines hurt -> each wave-iteration is one LATENCY QUANTUM
// (issue loads, wait-all, compute); time ~ quanta x quantum. Levers: fewer
// quanta, cheaper quanta.
// R11: wave-aligned 240-element windows (= 16 cells = 60 lanes x float4,
//    window start % 15 == 0) -> every gate element lives INSIDE the wave's
//    own loads: gates via 2 intra-wave __shfl from the owning lane. Gate
//    gathers GONE (4 VMEM/iter -> pure streams). Window-relative slot
//    masks / donor lanes / gate positions are per-lane constants hoisted
//    out of the loop (per-iter magic-div VALU gone). TWO windows per
//    iteration (4 independent stream loads per wait) -> 7 quanta vs R7's
//    12. Grid 1792 x 7 iters x 1920 elem = n exactly; 7 blocks/CU all
//    resident; 60/64 lanes active (-6%).

#define EPSF 1e-9f
#define LN2F 0.69314718055994530942f

#define GRID    1792
#define KITERS  7
#define BLK_E   (KITERS * 1920)        // 13,440 elements per block
#define FAST_N  (GRID * BLK_E)         // 24,084,480 floats

typedef float f32x4 __attribute__((ext_vector_type(4)));

__device__ __forceinline__ float bce_of(float ox, float tx) {
    const float l1 = __log2f(ox + EPSF);
    const float l2 = __log2f((1.f - ox) + EPSF);
    return -LN2F * (tx * l1 + (1.f - tx) * l2);
}

// ---------- fast path: wave-aligned windows, shuffle gates ----------
__global__ __launch_bounds__(256, 7) void yolo_loss_wave(
    const float* __restrict__ o, const float* __restrict__ t,
    float* __restrict__ out_sum)
{
    const int tid  = threadIdx.x;
    const int lane = tid & 63;
    const int wv   = tid >> 6;              // wave id 0..3
    const bool act = lane < 60;             // 60 lanes x float4 = 240 elems

    const f32x4* o4 = (const f32x4*)o;
    const f32x4* t4 = (const f32x4*)t;

    // ---- hoisted per-lane constants (window-relative layout repeats) ----
    const unsigned le  = 4u * (unsigned)lane;     // local element base
    const unsigned c0r = le / 15u;                // local cell of elem 0
    const unsigned c3r = (le + 3u) / 15u;         // local cell of elem 3
    const unsigned s0  = le - c0r * 15u;          // slot of elem 0
    const int d_lo = (int)((15u * c0r) >> 2);     // donor lane for gate(c0r)
    const int d_hi = (int)((15u * c3r) >> 2);     // donor lane for gate(c3r)
    const unsigned j_own = (le + 14u) / 15u;      // gate id this lane may own
    const unsigned gpos  = 15u * j_own - le;      // its position 0..3 iff owner

    bool is4[4], ksq[4], kz[4], wr[4];
    #pragma unroll
    for (int j = 0; j < 4; ++j) {
        const unsigned s = s0 + (unsigned)j;          // s in [0,17]
        is4[j] = (s == 4u);                           // confidence -> BCE
        ksq[j] = (s == 2u) | (s == 3u) | (s == 17u);  // w/h -> sqrt term
        kz [j] = (s == 1u) | (s == 14u) | (s == 16u); // zeroed slots
        wr [j] = (s >= 15u);                          // next cell's gate
    }

    // per-window compute: gates via intra-wave shuffle, masks hoisted
    auto window_sum = [&](f32x4 ov, f32x4 tv) -> float {
        // donor value: the gate element inside this lane's own float4
        const float gA   = (gpos & 1u) ? ov.y : ov.x;
        const float gB   = (gpos & 1u) ? ov.w : ov.z;
        const float gown = (gpos & 2u) ? gB : gA;
        const float glo  = __shfl(gown, d_lo, 64);
        const float ghi  = __shfl(gown, d_hi, 64);

        const float oe[4] = {ov.x, ov.y, ov.z, ov.w};
        const float te[4] = {tv.x, tv.y, tv.z, tv.w};

        // confidence element select -> 1 BCE per float4
        float oc = oe[3], tc = te[3];
        #pragma unroll
        for (int j = 2; j >= 0; --j) { oc = is4[j] ? oe[j] : oc; tc = is4[j] ? te[j] : tc; }
        const float bce = bce_of(oc, tc);   // garbage-safe: inputs in (0,1)

        float sum = 0.f;
        #pragma unroll
        for (int j = 0; j < 4; ++j) {
            const float gate = wr[j] ? ghi : glo;
            const float ox = oe[j], tx = te[j];
            const float d  = ox - tx;
            const float sq = d * d;
            const float s23 = (ox + tx) - 2.f * __builtin_amdgcn_sqrtf(ox * tx);
            float c = ksq[j] ? s23 : sq;
            c = is4[j] ? bce : c;
            c = kz[j] ? 0.f : c;
            c = (gate != 0.f) ? c : 0.f;
            sum += c;
        }
        return sum;
    };

    const unsigned blk_f4 = blockIdx.x * (unsigned)(BLK_E / 4);
    float acc = 0.f;
    #pragma unroll
    for (int k = 0; k < KITERS; ++k) {
        // this wave's pair of windows, f4 units (A at +0, B at +60 f4s)
        const unsigned wbase = blk_f4 + (unsigned)k * 480u + (unsigned)wv * 120u;
        f32x4 ovA = {0.f,0.f,0.f,0.f}, tvA = {0.f,0.f,0.f,0.f};
        f32x4 ovB = {0.f,0.f,0.f,0.f}, tvB = {0.f,0.f,0.f,0.f};
        if (act) {                       // 4 independent streams, one wait
            ovA = o4[wbase + (unsigned)lane];
            tvA = t4[wbase + (unsigned)lane];
            ovB = o4[wbase + 60u + (unsigned)lane];
            tvB = t4[wbase + 60u + (unsigned)lane];
        }
        const float sA = window_sum(ovA, tvA);   // all 64 lanes run shuffles
        const float sB = window_sum(ovB, tvB);
        acc += act ? (sA + sB) : 0.f;
    }

    #pragma unroll
    for (int off = 32; off; off >>= 1) acc += __shfl_down(acc, off, 64);
    __shared__ float wsum[4];
    if ((tid & 63) == 0) wsum[tid >> 6] = acc;
    __syncthreads();
    if (tid == 0) atomicAdd(out_sum, wsum[0] + wsum[1] + wsum[2] + wsum[3]);
}

// ---------- generic fallback (any n): R5-style guarded grid-stride ----------
__global__ __launch_bounds__(256) void yolo_loss_generic(
    const float* __restrict__ o, const float* __restrict__ t,
    float* __restrict__ out_sum, int n4, int n)
{
    const int tid = threadIdx.x;
    const int stride = gridDim.x * 256;
    const float4* o4 = (const float4*)o;
    const float4* t4 = (const float4*)t;
    float acc = 0.f;

    for (int i = blockIdx.x * 256 + tid; i < n4; i += stride) {
        const float4 ov = o4[i];
        const float4 tv = t4[i];
        const unsigned e0 = (unsigned)i * 4u;
        const unsigned c0 = e0 / 15u;
        const unsigned c3 = (e0 + 3u) / 15u;
        const unsigned s0 = e0 - c0 * 15u;
        const float glo = o[c0 * 15u], ghi = o[c3 * 15u];
        const float oe[4] = {ov.x, ov.y, ov.z, ov.w};
        const float te[4] = {tv.x, tv.y, tv.z, tv.w};
        #pragma unroll
        for (int j = 0; j < 4; ++j) {
            unsigned s = s0 + (unsigned)j;
            const bool wrap = s >= 15u;
            s = wrap ? s - 15u : s;
            const float gate = wrap ? ghi : glo;
            const float ox = oe[j], tx = te[j];
            const float d = ox - tx;
            const float sq = d * d;
            const float s23 = (ox + tx) - 2.f * __builtin_amdgcn_sqrtf(ox * tx);
            float c = ((s == 2u) | (s == 3u)) ? s23 : sq;
            c = (s == 4u) ? bce_of(ox, tx) : c;
            c = ((s == 1u) | (s == 14u)) ? 0.f : c;
            c = (gate != 0.f) ? c : 0.f;
            acc += c;
        }
    }
    const int tail0 = n4 * 4;
    if (blockIdx.x == 0 && tid < n - tail0) {
        const unsigned e = (unsigned)(tail0 + tid);
        const unsigned cell = e / 15u;
        const unsigned s = e - cell * 15u;
        const float gate = o[cell * 15u];
        const float ox = o[e], tx = t[e];
        const float d = ox - tx;
        float c = d * d;
        c = ((s == 2u) | (s == 3u)) ? (ox + tx) - 2.f * __builtin_amdgcn_sqrtf(ox * tx) : c;
        c = (s == 4u) ? bce_of(ox, tx) : c;
        c = ((s == 1u) | (s == 14u)) ? 0.f : c;
        c = (gate != 0.f) ? c : 0.f;
        acc += c;
    }
    #pragma unroll
    for (int off = 32; off; off >>= 1) acc += __shfl_down(acc, off, 64);
    __shared__ float wsum[4];
    if ((tid & 63) == 0) wsum[tid >> 6] = acc;
    __syncthreads();
    if (tid == 0) atomicAdd(out_sum, wsum[0] + wsum[1] + wsum[2] + wsum[3]);
}

extern "C" void kernel_launch(void* const* d_in, const int* in_sizes, int n_in,
                              void* d_out, int out_size, void* d_ws, size_t ws_size,
                              hipStream_t stream) {
    const float* o = (const float*)d_in[0];
    const float* t = (const float*)d_in[1];
    float* out = (float*)d_out;
    const int n = in_sizes[0];

    // d_out is poisoned 0xAA before every timed replay -> zero it on-stream.
    hipMemsetAsync(out, 0, sizeof(float), stream);

    if (n == FAST_N) {
        yolo_loss_wave<<<GRID, 256, 0, stream>>>(o, t, out);
    } else {
        yolo_loss_generic<<<2940, 256, 0, stream>>>(o, t, out, n / 4, n);
    }
}

// Round 6
// 208.424 us; speedup vs baseline: 1.2547x; 1.2547x over previous
//
#include <hip/hip_runtime.h>

// YOLO loss reduction: B=512, 3136 cells/sample, 15 slots/cell, fp32, sum.
//
// History: R5 slot-stream 76us. R6 batch-8 reg pipeline 72us (collapsed,
// VGPR=60). R7 depth-2 reg + residency 71us (collapsed, VGPR=20; occupancy
// 32->53%, dur unchanged). R9 LDS pipeline 86us (barrier convoy). R10 asm
// depth-4 ring 86us (VGPR=28, ring bounced through scratch). R11 wave-
// aligned windows + shuffle gates 130us REGRESSION -- but counters showed
// WRITE_SIZE=205MB = 28 float4/thread: full k-unroll hoisted all 28 loads,
// blew the VGPR cap, spilled every vector to scratch (FETCH 172MB too).
// The window/shuffle math itself PASSED (absmax 0). Side datum: machine
// sustained ~3TB/s mixed traffic during the spill.
// R12: R11 unmasked. Identical math; #pragma unroll 1 on the k-loop so the
//    compiler cannot hoist-and-spill. Per iter: 4 independent 16B stream
//    loads -> one implicit wait -> compute 2 windows. Gates via intra-wave
//    __shfl (zero gather VMEM); slot masks / donor lanes / gate positions
//    hoisted per-lane constants; no LDS, no barriers. 7 quanta/wave vs
//    R7's 12, and each quantum is VALU-slimmer. Grid 1792 x 7 iters x
//    1920 elem = n exactly; 7 blocks/CU; 60/64 lanes active.
//    A/B read: ~50us => quantum model right; ~70us => converged evidence
//    for the ~2.7TB/s effective-service wall.

#define EPSF 1e-9f
#define LN2F 0.69314718055994530942f

#define GRID    1792
#define KITERS  7
#define BLK_E   (KITERS * 1920)        // 13,440 elements per block
#define FAST_N  (GRID * BLK_E)         // 24,084,480 floats

typedef float f32x4 __attribute__((ext_vector_type(4)));

__device__ __forceinline__ float bce_of(float ox, float tx) {
    const float l1 = __log2f(ox + EPSF);
    const float l2 = __log2f((1.f - ox) + EPSF);
    return -LN2F * (tx * l1 + (1.f - tx) * l2);
}

// ---------- fast path: wave-aligned windows, shuffle gates, unroll 1 ----------
__global__ __launch_bounds__(256, 7) void yolo_loss_wave(
    const float* __restrict__ o, const float* __restrict__ t,
    float* __restrict__ out_sum)
{
    const int tid  = threadIdx.x;
    const int lane = tid & 63;
    const int wv   = tid >> 6;              // wave id 0..3
    const bool act = lane < 60;             // 60 lanes x float4 = 240 elems

    const f32x4* o4 = (const f32x4*)o;
    const f32x4* t4 = (const f32x4*)t;

    // ---- hoisted per-lane constants (window-relative layout repeats) ----
    const unsigned le  = 4u * (unsigned)lane;     // local element base
    const unsigned c0r = le / 15u;                // local cell of elem 0
    const unsigned c3r = (le + 3u) / 15u;         // local cell of elem 3
    const unsigned s0  = le - c0r * 15u;          // slot of elem 0
    const int d_lo = (int)((15u * c0r) >> 2);     // donor lane for gate(c0r)
    const int d_hi = (int)((15u * c3r) >> 2);     // donor lane for gate(c3r)
    const unsigned j_own = (le + 14u) / 15u;      // gate id this lane may own
    const unsigned gpos  = 15u * j_own - le;      // its position 0..3 iff owner
    const bool gsel1 = (gpos & 1u) != 0u;
    const bool gsel2 = (gpos & 2u) != 0u;

    bool is4[4], ksq[4], kz[4], wr[4];
    #pragma unroll
    for (int j = 0; j < 4; ++j) {
        const unsigned s = s0 + (unsigned)j;          // s in [0,17]
        is4[j] = (s == 4u);                           // confidence -> BCE
        ksq[j] = (s == 2u) | (s == 3u) | (s == 17u);  // w/h -> sqrt term
        kz [j] = (s == 1u) | (s == 14u) | (s == 16u); // zeroed slots
        wr [j] = (s >= 15u);                          // next cell's gate
    }

    // per-window compute: gates via intra-wave shuffle, masks hoisted
    auto window_sum = [&](f32x4 ov, f32x4 tv) -> float {
        // donor value: the gate element inside this lane's own float4
        const float gA   = gsel1 ? ov.y : ov.x;
        const float gB   = gsel1 ? ov.w : ov.z;
        const float gown = gsel2 ? gB : gA;
        const float glo  = __shfl(gown, d_lo, 64);
        const float ghi  = __shfl(gown, d_hi, 64);

        const float oe[4] = {ov.x, ov.y, ov.z, ov.w};
        const float te[4] = {tv.x, tv.y, tv.z, tv.w};

        // confidence element select -> 1 BCE per float4
        float oc = oe[3], tc = te[3];
        #pragma unroll
        for (int j = 2; j >= 0; --j) { oc = is4[j] ? oe[j] : oc; tc = is4[j] ? te[j] : tc; }
        const float bce = bce_of(oc, tc);   // garbage-safe: inputs in (0,1)

        float sum = 0.f;
        #pragma unroll
        for (int j = 0; j < 4; ++j) {
            const float gate = wr[j] ? ghi : glo;
            const float ox = oe[j], tx = te[j];
            const float d  = ox - tx;
            const float sq = d * d;
            const float s23 = (ox + tx) - 2.f * __builtin_amdgcn_sqrtf(ox * tx);
            float c = ksq[j] ? s23 : sq;
            c = is4[j] ? bce : c;
            c = kz[j] ? 0.f : c;
            c = (gate != 0.f) ? c : 0.f;
            sum += c;
        }
        return sum;
    };

    const unsigned blk_f4 = blockIdx.x * (unsigned)(BLK_E / 4);
    float acc = 0.f;
    #pragma unroll 1                       // CRITICAL: no hoist-all-loads spill
    for (int k = 0; k < KITERS; ++k) {
        // this wave's pair of windows, f4 units (A at +0, B at +60 f4s)
        const unsigned wbase = blk_f4 + (unsigned)k * 480u + (unsigned)wv * 120u;
        f32x4 ovA = {0.f,0.f,0.f,0.f}, tvA = {0.f,0.f,0.f,0.f};
        f32x4 ovB = {0.f,0.f,0.f,0.f}, tvB = {0.f,0.f,0.f,0.f};
        if (act) {                          // 4 independent streams, one wait
            ovA = o4[wbase + (unsigned)lane];
            tvA = t4[wbase + (unsigned)lane];
            ovB = o4[wbase + 60u + (unsigned)lane];
            tvB = t4[wbase + 60u + (unsigned)lane];
        }
        const float sA = window_sum(ovA, tvA);   // all 64 lanes run shuffles
        const float sB = window_sum(ovB, tvB);
        acc += act ? (sA + sB) : 0.f;
    }

    #pragma unroll
    for (int off = 32; off; off >>= 1) acc += __shfl_down(acc, off, 64);
    __shared__ float wsum[4];
    if ((tid & 63) == 0) wsum[tid >> 6] = acc;
    __syncthreads();
    if (tid == 0) atomicAdd(out_sum, wsum[0] + wsum[1] + wsum[2] + wsum[3]);
}

// ---------- generic fallback (any n): R5-style guarded grid-stride ----------
__global__ __launch_bounds__(256) void yolo_loss_generic(
    const float* __restrict__ o, const float* __restrict__ t,
    float* __restrict__ out_sum, int n4, int n)
{
    const int tid = threadIdx.x;
    const int stride = gridDim.x * 256;
    const float4* o4 = (const float4*)o;
    const float4* t4 = (const float4*)t;
    float acc = 0.f;

    for (int i = blockIdx.x * 256 + tid; i < n4; i += stride) {
        const float4 ov = o4[i];
        const float4 tv = t4[i];
        const unsigned e0 = (unsigned)i * 4u;
        const unsigned c0 = e0 / 15u;
        const unsigned c3 = (e0 + 3u) / 15u;
        const unsigned s0 = e0 - c0 * 15u;
        const float glo = o[c0 * 15u], ghi = o[c3 * 15u];
        const float oe[4] = {ov.x, ov.y, ov.z, ov.w};
        const float te[4] = {tv.x, tv.y, tv.z, tv.w};
        #pragma unroll
        for (int j = 0; j < 4; ++j) {
            unsigned s = s0 + (unsigned)j;
            const bool wrap = s >= 15u;
            s = wrap ? s - 15u : s;
            const float gate = wrap ? ghi : glo;
            const float ox = oe[j], tx = te[j];
            const float d = ox - tx;
            const float sq = d * d;
            const float s23 = (ox + tx) - 2.f * __builtin_amdgcn_sqrtf(ox * tx);
            float c = ((s == 2u) | (s == 3u)) ? s23 : sq;
            c = (s == 4u) ? bce_of(ox, tx) : c;
            c = ((s == 1u) | (s == 14u)) ? 0.f : c;
            c = (gate != 0.f) ? c : 0.f;
            acc += c;
        }
    }
    const int tail0 = n4 * 4;
    if (blockIdx.x == 0 && tid < n - tail0) {
        const unsigned e = (unsigned)(tail0 + tid);
        const unsigned cell = e / 15u;
        const unsigned s = e - cell * 15u;
        const float gate = o[cell * 15u];
        const float ox = o[e], tx = t[e];
        const float d = ox - tx;
        float c = d * d;
        c = ((s == 2u) | (s == 3u)) ? (ox + tx) - 2.f * __builtin_amdgcn_sqrtf(ox * tx) : c;
        c = (s == 4u) ? bce_of(ox, tx) : c;
        c = ((s == 1u) | (s == 14u)) ? 0.f : c;
        c = (gate != 0.f) ? c : 0.f;
        acc += c;
    }
    #pragma unroll
    for (int off = 32; off; off >>= 1) acc += __shfl_down(acc, off, 64);
    __shared__ float wsum[4];
    if ((tid & 63) == 0) wsum[tid >> 6] = acc;
    __syncthreads();
    if (tid == 0) atomicAdd(out_sum, wsum[0] + wsum[1] + wsum[2] + wsum[3]);
}

extern "C" void kernel_launch(void* const* d_in, const int* in_sizes, int n_in,
                              void* d_out, int out_size, void* d_ws, size_t ws_size,
                              hipStream_t stream) {
    const float* o = (const float*)d_in[0];
    const float* t = (const float*)d_in[1];
    float* out = (float*)d_out;
    const int n = in_sizes[0];

    // d_out is poisoned 0xAA before every timed replay -> zero it on-stream.
    hipMemsetAsync(out, 0, sizeof(float), stream);

    if (n == FAST_N) {
        yolo_loss_wave<<<GRID, 256, 0, stream>>>(o, t, out);
    } else {
        yolo_loss_generic<<<2940, 256, 0, stream>>>(o, t, out, n / 4, n);
    }
}

// Round 7
// 204.974 us; speedup vs baseline: 1.2759x; 1.0168x over previous
//
#include <hip/hip_runtime.h>

// YOLO loss reduction: B=512, 3136 cells/sample, 15 slots/cell, fp32, sum.
//
// History: R5 76us. R6 batch-8 reg pipeline 72us (collapsed VGPR=60). R7
// depth-2 reg 71us (collapsed VGPR=20; occupancy 32->53%, dur flat). R9
// LDS pipeline 86us (4-wave s_barrier lockstep + ahead-1). R10 asm ring
// 86us (AGPR-bounced). R11 windows+shuffle 130us (unroll hoist-spill,
// WRITE 205MB). R12 = R11 with unroll-1: 76us, VGPR=16 -> compiler AGAIN
// rewrote 4-loads-one-wait into load-pair/wait pairs. Conclusion: any
// VGPR-destined load gets its wait tightened by regalloc; per-wave MLP is
// pinned at ~2. R11 spill datum: machine served ~3.0TB/s when given more
// outstanding requests -> demand-limited, not a HW wall.
// R13: the one load path regalloc can't touch: global_load_lds (dest=LDS,
//    no VGPRs, vmcnt-ordered). R9's mistakes removed: WAVE-PRIVATE rings
//    (zero s_barrier anywhere in the loop) + depth-4/ahead-3 (vmcnt(6)
//    steady-state, never 0 mid-loop). Wave-aligned 240-el (16-cell)
//    windows: gates live inside the wave's own window -> ds_read, masks/
//    offsets hoisted per-lane constants (R12-verified math). 6 KB-loads
//    in flight/wave, ~96KB/CU outstanding (~3x R7). Grid 1792 x 14
//    stages x 960 el = n exactly; LDS 33KB -> 4 blocks/CU.

#define EPSF 1e-9f
#define LN2F 0.69314718055994530942f

#define GRID    1792
#define NSTAGE  14                     // 960 elements (= 4 waves x 240) per stage
#define BLK_E   (NSTAGE * 960)         // 13,440 elements per block
#define FAST_N  (GRID * BLK_E)         // 24,084,480 floats

typedef float f32x4 __attribute__((ext_vector_type(4)));

__device__ __forceinline__ float bce_of(float ox, float tx) {
    const float l1 = __log2f(ox + EPSF);
    const float l2 = __log2f((1.f - ox) + EPSF);
    return -LN2F * (tx * l1 + (1.f - tx) * l2);
}

// ---------- fast path: wave-private async-LDS rings, no barriers ----------
__global__ __launch_bounds__(256) void yolo_loss_alds(
    const float* __restrict__ o, const float* __restrict__ t,
    float* __restrict__ out_sum)
{
    __shared__ f32x4 obuf[4][4][64];   // [ring slot][wave][lane] 16,384 B
    __shared__ f32x4 tbuf[4][4][64];   // 16,384 B
    __shared__ float wsum[4];

    const int tid  = threadIdx.x;
    const int lane = tid & 63;
    const int wv   = tid >> 6;              // wave id 0..3
    const bool act = lane < 60;             // 60 lanes x float4 = 240 elems

    const f32x4* o4 = (const f32x4*)o;
    const f32x4* t4 = (const f32x4*)t;

    // ---- hoisted per-lane constants (window starts at element%15==0) ----
    const unsigned le  = 4u * (unsigned)lane;     // local element base
    const unsigned c0r = le / 15u;                // local cell of elem 0
    const unsigned c3r = (le + 3u) / 15u;         // local cell of elem 3
    const unsigned s0  = le - c0r * 15u;          // slot of elem 0
    const unsigned glo_off = c0r * 15u;           // gate float idx in window
    const unsigned ghi_off = c3r * 15u;           // (<=240, stays in wave buf)

    bool is4[4], ksq[4], kz[4], wr[4];
    #pragma unroll
    for (int j = 0; j < 4; ++j) {
        const unsigned s = s0 + (unsigned)j;          // s in [0,17]
        is4[j] = (s == 4u);                           // confidence -> BCE
        ksq[j] = (s == 2u) | (s == 3u) | (s == 17u);  // w/h -> sqrt term
        kz [j] = (s == 1u) | (s == 14u) | (s == 16u); // zeroed slots
        wr [j] = (s >= 15u);                          // next cell's gate
    }

    // wave's f4 base for stage kk: blk + kk*240 + wv*60
    const unsigned wv_f4 = blockIdx.x * (unsigned)(BLK_E / 4) + (unsigned)wv * 60u;

    // ---- issue one stage: 2 global_load_lds, dest = this wave's ring slot ----
    auto issue = [&](int kk) {
        const int slot = kk & 3;
        if (act) {
            const unsigned g = wv_f4 + (unsigned)kk * 240u + (unsigned)lane;
            __builtin_amdgcn_global_load_lds((const void*)(o4 + g),
                                             (void*)&obuf[slot][wv][0], 16, 0, 0);
            __builtin_amdgcn_global_load_lds((const void*)(t4 + g),
                                             (void*)&tbuf[slot][wv][0], 16, 0, 0);
        }
    };

    // ---- consume one stage from the wave's own LDS (no cross-wave data) ----
    auto consume = [&](int kk) -> float {
        const int slot = kk & 3;
        const f32x4 ov = obuf[slot][wv][lane];
        const f32x4 tv = tbuf[slot][wv][lane];
        const float* owin = (const float*)&obuf[slot][wv][0];
        const float glo = owin[glo_off];
        const float ghi = owin[ghi_off];

        const float oe[4] = {ov.x, ov.y, ov.z, ov.w};
        const float te[4] = {tv.x, tv.y, tv.z, tv.w};

        // confidence element select -> 1 BCE per float4
        float oc = oe[3], tc = te[3];
        #pragma unroll
        for (int j = 2; j >= 0; --j) { oc = is4[j] ? oe[j] : oc; tc = is4[j] ? te[j] : tc; }
        const float bce = bce_of(oc, tc);   // garbage-safe: inputs in (0,1)

        float sum = 0.f;
        #pragma unroll
        for (int j = 0; j < 4; ++j) {
            const float gate = wr[j] ? ghi : glo;
            const float ox = oe[j], tx = te[j];
            const float d  = ox - tx;
            const float sq = d * d;
            const float s23 = (ox + tx) - 2.f * __builtin_amdgcn_sqrtf(ox * tx);
            float c = ksq[j] ? s23 : sq;
            c = is4[j] ? bce : c;
            c = kz[j] ? 0.f : c;
            c = (gate != 0.f) ? c : 0.f;
            sum += c;
        }
        return act ? sum : 0.f;             // lanes 60-63 computed garbage
    };

    // prologue: stages 0,1,2 in flight (6 loads)
    issue(0); issue(1); issue(2);

    float acc = 0.f;
    #pragma unroll 1
    for (int k = 0; k < NSTAGE - 3; ++k) {
        issue(k + 3);                                      // 8 in flight
        asm volatile("s_waitcnt vmcnt(6)" ::: "memory");   // stage k landed
        __builtin_amdgcn_sched_barrier(0);
        acc += consume(k);
    }
    // tail: drain 3 remaining stages with counted waits
    asm volatile("s_waitcnt vmcnt(4)" ::: "memory");
    __builtin_amdgcn_sched_barrier(0);
    acc += consume(NSTAGE - 3);
    asm volatile("s_waitcnt vmcnt(2)" ::: "memory");
    __builtin_amdgcn_sched_barrier(0);
    acc += consume(NSTAGE - 2);
    asm volatile("s_waitcnt vmcnt(0)" ::: "memory");
    __builtin_amdgcn_sched_barrier(0);
    acc += consume(NSTAGE - 1);

    // ---- block reduction (first barrier in the kernel) ----
    #pragma unroll
    for (int off = 32; off; off >>= 1) acc += __shfl_down(acc, off, 64);
    if (lane == 0) wsum[wv] = acc;
    __syncthreads();
    if (tid == 0) atomicAdd(out_sum, wsum[0] + wsum[1] + wsum[2] + wsum[3]);
}

// ---------- generic fallback (any n): R5-style guarded grid-stride ----------
__global__ __launch_bounds__(256) void yolo_loss_generic(
    const float* __restrict__ o, const float* __restrict__ t,
    float* __restrict__ out_sum, int n4, int n)
{
    const int tid = threadIdx.x;
    const int stride = gridDim.x * 256;
    const float4* o4 = (const float4*)o;
    const float4* t4 = (const float4*)t;
    float acc = 0.f;

    for (int i = blockIdx.x * 256 + tid; i < n4; i += stride) {
        const float4 ov = o4[i];
        const float4 tv = t4[i];
        const unsigned e0 = (unsigned)i * 4u;
        const unsigned c0 = e0 / 15u;
        const unsigned c3 = (e0 + 3u) / 15u;
        const unsigned s0 = e0 - c0 * 15u;
        const float glo = o[c0 * 15u], ghi = o[c3 * 15u];
        const float oe[4] = {ov.x, ov.y, ov.z, ov.w};
        const float te[4] = {tv.x, tv.y, tv.z, tv.w};
        #pragma unroll
        for (int j = 0; j < 4; ++j) {
            unsigned s = s0 + (unsigned)j;
            const bool wrap = s >= 15u;
            s = wrap ? s - 15u : s;
            const float gate = wrap ? ghi : glo;
            const float ox = oe[j], tx = te[j];
            const float d = ox - tx;
            const float sq = d * d;
            const float s23 = (ox + tx) - 2.f * __builtin_amdgcn_sqrtf(ox * tx);
            float c = ((s == 2u) | (s == 3u)) ? s23 : sq;
            c = (s == 4u) ? bce_of(ox, tx) : c;
            c = ((s == 1u) | (s == 14u)) ? 0.f : c;
            c = (gate != 0.f) ? c : 0.f;
            acc += c;
        }
    }
    const int tail0 = n4 * 4;
    if (blockIdx.x == 0 && tid < n - tail0) {
        const unsigned e = (unsigned)(tail0 + tid);
        const unsigned cell = e / 15u;
        const unsigned s = e - cell * 15u;
        const float gate = o[cell * 15u];
        const float ox = o[e], tx = t[e];
        const float d = ox - tx;
        float c = d * d;
        c = ((s == 2u) | (s == 3u)) ? (ox + tx) - 2.f * __builtin_amdgcn_sqrtf(ox * tx) : c;
        c = (s == 4u) ? bce_of(ox, tx) : c;
        c = ((s == 1u) | (s == 14u)) ? 0.f : c;
        c = (gate != 0.f) ? c : 0.f;
        acc += c;
    }
    #pragma unroll
    for (int off = 32; off; off >>= 1) acc += __shfl_down(acc, off, 64);
    __shared__ float wsum[4];
    if ((tid & 63) == 0) wsum[tid >> 6] = acc;
    __syncthreads();
    if (tid == 0) atomicAdd(out_sum, wsum[0] + wsum[1] + wsum[2] + wsum[3]);
}

extern "C" void kernel_launch(void* const* d_in, const int* in_sizes, int n_in,
                              void* d_out, int out_size, void* d_ws, size_t ws_size,
                              hipStream_t stream) {
    const float* o = (const float*)d_in[0];
    const float* t = (const float*)d_in[1];
    float* out = (float*)d_out;
    const int n = in_sizes[0];

    // d_out is poisoned 0xAA before every timed replay -> zero it on-stream.
    hipMemsetAsync(out, 0, sizeof(float), stream);

    if (n == FAST_N) {
        yolo_loss_alds<<<GRID, 256, 0, stream>>>(o, t, out);
    } else {
        yolo_loss_generic<<<2940, 256, 0, stream>>>(o, t, out, n / 4, n);
    }
}